// Round 2
// baseline (6886.643 us; speedup 1.0000x reference)
//
#include <hip/hip_runtime.h>
#include <hip/hip_bf16.h>

#define B_ 1024
#define S_ 1000
#define F_ 63
#define H_ 512
#define OUT_ 2
#define M_ 16            // batch rows per block
#define NBLK (B_ / M_)   // 64 blocks
#define THREADS 512
#define NWAVE 8

typedef __attribute__((ext_vector_type(8))) __bf16 bf16x8;
typedef __attribute__((ext_vector_type(4))) float f32x4;
static_assert(sizeof(bf16x8) == 16, "bf16x8 must be 16B");

__device__ __forceinline__ unsigned short f2bf(float f) {
  union { float f; unsigned u; } v; v.f = f;
  unsigned r = v.u + 0x7FFF + ((v.u >> 16) & 1);   // RNE
  return (unsigned short)(r >> 16);
}
__device__ __forceinline__ unsigned packbf(float a, float b) {
  return (unsigned)f2bf(a) | ((unsigned)f2bf(b) << 16);
}

// ---------- prep: W2 (512x512 f32, [k][n]) -> W2t bf16 [n][k] ----------
__global__ void k_prep_w2(const float* __restrict__ W2, unsigned short* __restrict__ W2t) {
  __shared__ float tile[64][65];
  int bx = blockIdx.x & 7, by = blockIdx.x >> 3;   // 8x8 tiles of 64x64
  int r0 = by * 64, c0 = bx * 64;
  for (int rep = 0; rep < 16; rep++) {
    int idx = rep * 256 + threadIdx.x;
    int i = idx >> 6, j = idx & 63;
    tile[i][j] = W2[(r0 + i) * 512 + (c0 + j)];
  }
  __syncthreads();
  for (int rep = 0; rep < 16; rep++) {
    int idx = rep * 256 + threadIdx.x;
    int i = idx >> 6, j = idx & 63;                // out row c0+i, col r0+j
    W2t[(c0 + i) * 512 + (r0 + j)] = f2bf(tile[j][i]);
  }
}

// ---------- the scan ----------
// Each block owns 16 batch rows for all 1000 steps. 8 waves split the n(=512)
// dimension 8x64. Orientation: compute h^T (M-dim = n, N-dim = batch row r) so
// fragments are 8-contiguous-k reads and C packs as b64 writes.
__global__ __launch_bounds__(THREADS)
void k_scan(const float* __restrict__ x, const float* __restrict__ W0in,
            const float* __restrict__ sf, const float* __restrict__ W1,
            const float* __restrict__ b1, const unsigned short* __restrict__ W2t,
            const float* __restrict__ b2, const float* __restrict__ W3,
            const float* __restrict__ b3, float* __restrict__ out)
{
  __shared__ __attribute__((aligned(16))) unsigned short w1t[512 * 64]; // [n1][k] swz
  __shared__ __attribute__((aligned(16))) unsigned short zA[2][16 * 64]; // [buf][r][k] swz
  __shared__ __attribute__((aligned(16))) unsigned short h1A[16 * 512];  // [r][n1] swz
  __shared__ __attribute__((aligned(16))) float b1s[512];
  __shared__ __attribute__((aligned(16))) float b2s[512];
  __shared__ float2 w3s[512];
  __shared__ float2 dwred[NWAVE][16];
  __shared__ float2 wst[16];      // running W (f32!)
  __shared__ float x0s[2][16];
  __shared__ float cons[4];       // b3[0], b3[1], sf[0], sf[1]

  const int tid  = threadIdx.x;
  const int wid  = tid >> 6;
  const int lane = tid & 63;
  const int lr   = lane & 15;     // fragment row/col index
  const int g    = lane >> 4;     // 0..3
  const int b0   = blockIdx.x * M_;

  // ---- prologue: stage weights into LDS ----
  {
    int n = tid;                               // 0..511
    for (int k = 0; k < 64; k += 2) {
      float a = W1[k * 512 + n];
      float c = W1[(k + 1) * 512 + n];
      int off = n * 128 + (((k ^ ((n & 7) << 3))) << 1);
      *(unsigned*)((char*)w1t + off) = packbf(a, c);
    }
    b1s[tid] = b1[tid];
    b2s[tid] = b2[tid];
    w3s[tid] = make_float2(W3[tid * 2], W3[tid * 2 + 1]);
  }
  if (tid < 16) {
    float w0v = W0in[(b0 + tid) * 2], w1v = W0in[(b0 + tid) * 2 + 1];
    wst[tid] = make_float2(w0v, w1v);
    int off = tid * 128 + ((tid & 7) << 4);    // zoff(r,0)
    *(unsigned*)((char*)zA + off) = packbf(w0v, w1v);   // zA[0] W part
  }
  {
    int r = tid >> 5, l32 = tid & 31;
    long xb = (long)(b0 + r) * (S_ * F_);
    if (l32 < 31) {
      float a = x[xb + 1 + 2 * l32];
      float c = x[xb + 2 + 2 * l32];
      int k = 2 + 2 * l32;
      int off = r * 128 + ((k ^ ((r & 7) << 3)) << 1);
      *(unsigned*)((char*)zA + off) = packbf(a, c);     // zA[0] x part
    } else {
      x0s[0][r] = x[xb];
    }
  }
  if (tid < 4) cons[tid] = (tid < 2) ? b3[tid] : sf[tid - 2];
  __syncthreads();

  float* out_sig = out;                         // B*S
  float* out_dwl = out + (long)B_ * S_;         // B*2
  float* out_ws  = out + (long)B_ * S_ + B_ * OUT_; // B*S*2

  for (int t = 0; t < S_; t++) {
    const int cur = t & 1, nxt = cur ^ 1;

    // ---- prefetch x(t+1) into registers (consumed after B2) ----
    const int r5 = tid >> 5, l32 = tid & 31;
    float pf0 = 0.f, pf1 = 0.f, px0 = 0.f;
    if (t + 1 < S_) {
      long xb = (long)(b0 + r5) * (S_ * F_) + (long)(t + 1) * F_;
      if (l32 < 31) { pf0 = x[xb + 1 + 2 * l32]; pf1 = x[xb + 2 + 2 * l32]; }
      else          { px0 = x[xb]; }
    }

    // ---- L1: h1^T = W1^T(64->512 rows) @ z^T ; write h1A ----
    const char* zb = (const char*)zA + cur * 2048;
    bf16x8 bz0, bz1;
    {
      int o0 = lr * 128 + (((g * 8)      ^ ((lr & 7) << 3)) << 1);
      int o1 = lr * 128 + (((32 + g * 8) ^ ((lr & 7) << 3)) << 1);
      bz0 = __builtin_bit_cast(bf16x8, *(const int4*)(zb + o0));
      bz1 = __builtin_bit_cast(bf16x8, *(const int4*)(zb + o1));
    }
#pragma unroll
    for (int mt = 0; mt < 4; mt++) {
      int n1b = wid * 64 + mt * 16;
      int n1  = n1b + lr;
      int oa0 = n1 * 128 + (((g * 8)      ^ ((n1 & 7) << 3)) << 1);
      int oa1 = n1 * 128 + (((32 + g * 8) ^ ((n1 & 7) << 3)) << 1);
      bf16x8 a0 = __builtin_bit_cast(bf16x8, *(const int4*)((const char*)w1t + oa0));
      bf16x8 a1 = __builtin_bit_cast(bf16x8, *(const int4*)((const char*)w1t + oa1));
      f32x4 acc = {0.f, 0.f, 0.f, 0.f};
      acc = __builtin_amdgcn_mfma_f32_16x16x32_bf16(a0, bz0, acc, 0, 0, 0);
      acc = __builtin_amdgcn_mfma_f32_16x16x32_bf16(a1, bz1, acc, 0, 0, 0);
      int nr = n1b + g * 4;                      // C rows = nr..nr+3, col = lr
      float4 bb = *(const float4*)&b1s[nr];
      float h0 = fmaxf(acc[0] + bb.x, 0.f);
      float h1v = fmaxf(acc[1] + bb.y, 0.f);
      float h2v = fmaxf(acc[2] + bb.z, 0.f);
      float h3 = fmaxf(acc[3] + bb.w, 0.f);
      unsigned lo = packbf(h0, h1v), hi = packbf(h2v, h3);
      int ow = lr * 1024 + ((nr ^ ((lr & 7) << 3)) << 1);
      *(unsigned long long*)((char*)h1A + ow) =
          (unsigned long long)lo | ((unsigned long long)hi << 32);
    }
    __syncthreads();   // B1: h1A complete

    // ---- L2: h2^T = W2^T @ h1^T (K=512, A from global W2t) + L3 partials ----
    bf16x8 bh[16];
#pragma unroll
    for (int kt = 0; kt < 16; kt++) {
      int n = kt * 32 + g * 8;
      int o = lr * 1024 + ((n ^ ((lr & 7) << 3)) << 1);
      bh[kt] = __builtin_bit_cast(bf16x8, *(const int4*)((const char*)h1A + o));
    }
    float dw0 = 0.f, dw1 = 0.f;
#pragma unroll
    for (int mt = 0; mt < 4; mt++) {
      int n2b = wid * 64 + mt * 16;
      int n2  = n2b + lr;
      const char* wrow = (const char*)W2t + ((long)n2 * 512 + g * 8) * 2;
      f32x4 acc = {0.f, 0.f, 0.f, 0.f};
#pragma unroll
      for (int kt = 0; kt < 16; kt++) {
        bf16x8 a = __builtin_bit_cast(bf16x8, *(const int4*)(wrow + kt * 64));
        acc = __builtin_amdgcn_mfma_f32_16x16x32_bf16(a, bh[kt], acc, 0, 0, 0);
      }
      int nr = n2b + g * 4;
      float4 bb = *(const float4*)&b2s[nr];
      float bba[4] = {bb.x, bb.y, bb.z, bb.w};
#pragma unroll
      for (int i = 0; i < 4; i++) {
        float h = fmaxf(acc[i] + bba[i], 0.f);
        float2 w3v = w3s[nr + i];
        dw0 += h * w3v.x;
        dw1 += h * w3v.y;
      }
    }
    // reduce the g-groups (lanes xor 16, 32)
    dw0 += __shfl_xor(dw0, 16); dw1 += __shfl_xor(dw1, 16);
    dw0 += __shfl_xor(dw0, 32); dw1 += __shfl_xor(dw1, 32);
    if (lane < 16) dwred[wid][lane] = make_float2(dw0, dw1);
    __syncthreads();   // B2: dwred complete

    // ---- finalize (wave 0) : cross-wave reduce, W update, outputs ----
    if (wid == 0 && lane < 16) {
      int r = lane;
      float s0 = 0.f, s1 = 0.f;
#pragma unroll
      for (int w = 0; w < NWAVE; w++) { float2 p = dwred[w][r]; s0 += p.x; s1 += p.y; }
      float d0 = (s0 + cons[0]) * cons[2];
      float d1 = (s1 + cons[1]) * cons[3];
      float2 wc = wst[r];
      float w0n = wc.x + d0, w1n = wc.y + d1;
      wst[r] = make_float2(w0n, w1n);
      long oi = (long)(b0 + r) * S_ + t;
      out_ws[oi * 2]     = w0n;
      out_ws[oi * 2 + 1] = w1n;
      float zv = w0n * x0s[cur][r] + w1n;
      out_sig[oi] = 1.f / (1.f + expf(-zv));
      if (t == S_ - 1) { out_dwl[(b0 + r) * 2] = d0; out_dwl[(b0 + r) * 2 + 1] = d1; }
      if (t + 1 < S_) {  // zA[nxt] W part (new W, bf16)
        int off = nxt * 2048 + r * 128 + ((r & 7) << 4);
        *(unsigned*)((char*)zA + off) = packbf(w0n, w1n);
      }
    }
    // ---- all threads: zA[nxt] x part from prefetched regs ----
    if (t + 1 < S_) {
      char* znb = (char*)zA + nxt * 2048;
      if (l32 < 31) {
        int k = 2 + 2 * l32;
        int off = r5 * 128 + ((k ^ ((r5 & 7) << 3)) << 1);
        *(unsigned*)(znb + off) = packbf(pf0, pf1);
      } else {
        x0s[nxt][r5] = px0;
      }
    }
    __syncthreads();   // B0: zA[nxt], wst, x0s ready for next step
  }
}

extern "C" void kernel_launch(void* const* d_in, const int* in_sizes, int n_in,
                              void* d_out, int out_size, void* d_ws, size_t ws_size,
                              hipStream_t stream) {
  const float* x  = (const float*)d_in[0];
  const float* W0 = (const float*)d_in[1];
  const float* sf = (const float*)d_in[2];
  const float* W1 = (const float*)d_in[3];
  const float* b1 = (const float*)d_in[4];
  const float* W2 = (const float*)d_in[5];
  const float* b2 = (const float*)d_in[6];
  const float* W3 = (const float*)d_in[7];
  const float* b3 = (const float*)d_in[8];
  unsigned short* W2t = (unsigned short*)d_ws;   // 512*512*2B = 512 KB
  float* out = (float*)d_out;

  k_prep_w2<<<dim3(64), dim3(256), 0, stream>>>(W2, W2t);
  k_scan<<<dim3(NBLK), dim3(THREADS), 0, stream>>>(x, W0, sf, W1, b1, W2t, b2, W3, b3, out);
}